// Round 12
// baseline (236.045 us; speedup 1.0000x reference)
//
#include <hip/hip_runtime.h>
#include <hip/hip_bf16.h>
#include <stdint.h>

typedef unsigned short u16;
typedef unsigned int u32;
typedef __attribute__((ext_vector_type(8))) short short8;
typedef __attribute__((ext_vector_type(4))) float f32x4;

#define T_TOK 2048
#define H_DIM 1024
#define F_DIM 4096
#define E_NUM 8
#define M_SLOT 4096
#define MAXTILES 40
#define KSPLIT 4

__device__ __forceinline__ u16 f2bf(float f){
  union { float f; u32 u; } v; v.f = f;
  return (u16)((v.u + 0x7FFFu + ((v.u >> 16) & 1u)) >> 16);
}

__device__ __forceinline__ void gload_lds16(const void* g, void* l){
  __builtin_amdgcn_global_load_lds(
      (const __attribute__((address_space(1))) u32*)g,
      (__attribute__((address_space(3))) u32*)l, 16, 0, 0);
}

// ---------------- transpose body: [E][R][C] f32 -> [E][C][R] bf16 ----------------
template<int R, int C>
__device__ __forceinline__ void transpose_body(const float* __restrict__ in,
                                               u16* __restrict__ out,
                                               int cx, int ry, int e,
                                               u16 (*tile)[66]){
  const float* ip = in + (size_t)e * R * C;
  u16* op = out + (size_t)e * R * C;
  int c0 = cx * 64, r0 = ry * 64;
  int tr = threadIdx.x >> 4, tc = threadIdx.x & 15;
  #pragma unroll
  for (int i = 0; i < 4; i++){
    int r = tr + i * 16;
    float4 v = *(const float4*)(ip + (size_t)(r0 + r) * C + c0 + tc * 4);
    tile[r][tc*4+0] = f2bf(v.x); tile[r][tc*4+1] = f2bf(v.y);
    tile[r][tc*4+2] = f2bf(v.z); tile[r][tc*4+3] = f2bf(v.w);
  }
  __syncthreads();
  #pragma unroll
  for (int i = 0; i < 4; i++){
    int c = tr + i * 16;
    ushort4 o;
    o.x = tile[tc*4+0][c]; o.y = tile[tc*4+1][c];
    o.z = tile[tc*4+2][c]; o.w = tile[tc*4+3][c];
    *(ushort4*)(op + (size_t)(c0 + c) * R + r0 + tc * 4) = o;
  }
}

// ---------------- fused: router (512 blocks) + transpose-w1 (8192 blocks) ----
__global__ __launch_bounds__(256) void router_tw1_kernel(
    const float* __restrict__ x, const float* __restrict__ rw,
    int* __restrict__ tok_e, float* __restrict__ tok_p,
    const float* __restrict__ w1, u16* __restrict__ w1t){
  __shared__ __align__(16) char shbuf[E_NUM * H_DIM * 4];   // 32 KB union
  int bid = blockIdx.x;
  if (bid >= T_TOK / 4){
    int tb = bid - T_TOK / 4;        // 8192 blocks: w1 [E][1024][4096] -> w1t
    transpose_body<H_DIM, F_DIM>(w1, w1t, tb & 63, (tb >> 6) & 15, tb >> 10,
                                 (u16(*)[66])shbuf);
    return;
  }
  float* wlds = (float*)shbuf;
  int tid = threadIdx.x;
  for (int i = tid; i < H_DIM * E_NUM; i += 256){
    int h = i >> 3, e = i & 7;
    wlds[e * H_DIM + h] = rw[i];
  }
  __syncthreads();
  int wave = tid >> 6, lane = tid & 63;
  int t = bid * 4 + wave;
  const float* xr = x + (size_t)t * H_DIM;
  float acc[E_NUM];
  #pragma unroll
  for (int e = 0; e < E_NUM; e++) acc[e] = 0.f;
  for (int i = 0; i < H_DIM / 64; i++){
    float xv = xr[lane + 64 * i];
    #pragma unroll
    for (int e = 0; e < E_NUM; e++) acc[e] += xv * wlds[e * H_DIM + lane + 64 * i];
  }
  #pragma unroll
  for (int e = 0; e < E_NUM; e++){
    float r = acc[e];
    #pragma unroll
    for (int off = 32; off; off >>= 1) r += __shfl_xor(r, off, 64);
    acc[e] = r;
  }
  if (lane == 0){
    float l0 = acc[0]; int e0 = 0;
    #pragma unroll
    for (int e = 1; e < E_NUM; e++) if (acc[e] > l0){ l0 = acc[e]; e0 = e; }
    float l1 = -INFINITY; int e1 = 0;
    #pragma unroll
    for (int e = 0; e < E_NUM; e++) if (e != e0 && acc[e] > l1){ l1 = acc[e]; e1 = e; }
    float ex = expf(l1 - l0);
    float inv = 1.f / (1.f + ex);
    tok_e[2*t] = e0; tok_e[2*t+1] = e1;
    tok_p[2*t] = inv; tok_p[2*t+1] = ex * inv;
  }
}

// ---------------- fused hist+scan+scatter: ONE block, 256 threads ----------
__global__ __launch_bounds__(256) void route_pack_kernel(
    const int* __restrict__ tok_e, int* __restrict__ dest,
    int4* __restrict__ tiles, int* __restrict__ ntiles){
  __shared__ u32 part[64][E_NUM];
  __shared__ u32 base[64][E_NUM];
  int tid = threadIdx.x, lane = tid & 63, wv = tid >> 6;
  // phase 1: per-chunk expert counts (wave-uniform loops, full-wave ballots)
  for (int c = wv; c < 64; c += 4){
    int e = tok_e[c * 64 + lane];
    #pragma unroll
    for (int ee = 0; ee < E_NUM; ee++){
      unsigned long long mk = __ballot(e == ee);
      if (lane == ee) part[c][ee] = (u32)__popcll(mk);
    }
  }
  __syncthreads();
  // phase 2: wave 0 scans chunks (lane = chunk id)
  if (wv == 0){
    u32 exc[E_NUM], tot[E_NUM];
    #pragma unroll
    for (int e = 0; e < E_NUM; e++){
      u32 v = part[lane][e];
      u32 own = v;
      #pragma unroll
      for (int off = 1; off < 64; off <<= 1){
        u32 tu = __shfl_up(v, off, 64);
        if (lane >= off) v += tu;
      }
      exc[e] = v - own;
      tot[e] = __shfl(v, 63, 64);
    }
    u32 offs[E_NUM + 1]; offs[0] = 0;
    #pragma unroll
    for (int e = 0; e < E_NUM; e++) offs[e+1] = offs[e] + tot[e];
    #pragma unroll
    for (int e = 0; e < E_NUM; e++) base[lane][e] = offs[e] + exc[e];
    if (lane == 0){
      int nt = 0;
      for (int e = 0; e < E_NUM; e++){
        int cnt = (int)tot[e];
        for (int r0 = 0; r0 < cnt; r0 += 128){
          tiles[nt] = make_int4((int)offs[e] + r0, min(128, cnt - r0), e, 0);
          nt++;
        }
      }
      *ntiles = nt;
    }
  }
  __syncthreads();
  // phase 3: stable scatter
  for (int c = wv; c < 64; c += 4){
    int e = tok_e[c * 64 + lane];
    unsigned long long eq = 0;
    #pragma unroll
    for (int ee = 0; ee < E_NUM; ee++){
      unsigned long long mk = __ballot(e == ee);
      if (e == ee) eq = mk;
    }
    u32 rank = (u32)__popcll(eq & ((1ull << lane) - 1ull));
    dest[c * 64 + lane] = (int)(base[c][e] + rank);
  }
}

// ---------------- gather x rows -> grouped bf16 ----------------
__global__ __launch_bounds__(256) void gather_kernel(const float* __restrict__ x,
                                                     const int* __restrict__ dest,
                                                     u16* __restrict__ xg){
  int m = blockIdx.x;
  int d = dest[m];
  const float4* xr = (const float4*)(x + (size_t)(m >> 1) * H_DIM);
  float4 v = xr[threadIdx.x];
  ushort4 o;
  o.x = f2bf(v.x); o.y = f2bf(v.y); o.z = f2bf(v.z); o.w = f2bf(v.w);
  ((ushort4*)(xg + (size_t)d * H_DIM))[threadIdx.x] = o;
}

// ---------------- gemm97 body (r5 proven): 128x128, BK=64, 4 waves ----------
template<int N, int KSTRIDE, int NT, bool GELU_EP>
__device__ __forceinline__ void gemm_body(
    u16* As, u16* Bs,
    const u16* __restrict__ A, const u16* __restrict__ Bt,
    const int4* __restrict__ tiles, const int* __restrict__ ntiles_p,
    float* __restrict__ outF, u16* __restrict__ outB, size_t zstride,
    int colBlk, int tileBlk, int z){
  if (tileBlk >= *ntiles_p) return;
  int4 ti = tiles[tileBlk];
  int row0 = ti.x, nrows = ti.y, e = ti.z;
  int col0 = colBlk * 128;
  size_t kofs = (size_t)z * ((size_t)NT * 64);
  const u16* Be = Bt + (size_t)e * N * KSTRIDE;
  float* outFz = outF + (size_t)z * zstride;

  int lane = threadIdx.x & 63, wid = threadIdx.x >> 6;
  int wr = wid >> 1, wc = wid & 1;

  f32x4 acc[4][4];
  #pragma unroll
  for (int m = 0; m < 4; m++)
    #pragma unroll
    for (int n = 0; n < 4; n++) acc[m][n] = (f32x4)0.f;

  int srow = (wid << 3) + (lane >> 3);
  int skx  = ((lane & 7) * 16) ^ ((lane >> 3) << 4);

  for (int kt = 0; kt < NT; kt++){
    size_t kb = kofs + (size_t)kt * 64;
    #pragma unroll
    for (int i = 0; i < 4; i++){
      int row = i * 32 + srow;
      gload_lds16((const char*)(A  + (size_t)(row0 + row) * KSTRIDE + kb) + skx,
                  As + i * 2048 + wid * 512);
      gload_lds16((const char*)(Be + (size_t)(col0 + row) * KSTRIDE + kb) + skx,
                  Bs + i * 2048 + wid * 512);
    }
    __syncthreads();
    short8 a[4][2], b[4][2];
    #pragma unroll
    for (int m = 0; m < 4; m++){
      int row = wr * 64 + m * 16 + (lane & 15);
      #pragma unroll
      for (int kk = 0; kk < 2; kk++){
        int byte_ = row * 128 + ((kk * 64 + (lane >> 4) * 16) ^ ((row & 7) << 4));
        a[m][kk] = *(const short8*)((const char*)As + byte_);
      }
    }
    #pragma unroll
    for (int n = 0; n < 4; n++){
      int row = wc * 64 + n * 16 + (lane & 15);
      #pragma unroll
      for (int kk = 0; kk < 2; kk++){
        int byte_ = row * 128 + ((kk * 64 + (lane >> 4) * 16) ^ ((row & 7) << 4));
        b[n][kk] = *(const short8*)((const char*)Bs + byte_);
      }
    }
    #pragma unroll
    for (int m = 0; m < 4; m++)
      #pragma unroll
      for (int n = 0; n < 4; n++)
        #pragma unroll
        for (int kk = 0; kk < 2; kk++)
          acc[m][n] = __builtin_amdgcn_mfma_f32_16x16x32_bf16(a[m][kk], b[n][kk], acc[m][n], 0, 0, 0);
    __syncthreads();
  }

  #pragma unroll
  for (int m = 0; m < 4; m++){
    int rloc = wr * 64 + m * 16 + (lane >> 4) * 4;
    #pragma unroll
    for (int j = 0; j < 4; j++){
      int rr = rloc + j;
      if (rr < nrows){
        size_t rowg = (size_t)(row0 + rr);
        #pragma unroll
        for (int n = 0; n < 4; n++){
          int cc = col0 + wc * 64 + n * 16 + (lane & 15);
          float v = acc[m][n][j];
          if (GELU_EP){
            float g = v * 0.5f * (1.f + erff(v * 0.70710678118f));
            outFz[rowg * N + cc] = g;
            outB[rowg * N + cc] = f2bf(g);
          } else {
            outFz[rowg * N + cc] = v;
          }
        }
      }
    }
  }
}

// ---------------- fused: GEMM1 (bid<1280) + transpose-w2 (8192 blocks) ----
__global__ __launch_bounds__(256, 4) void gemm1_tw2_kernel(
    const u16* __restrict__ xg, const u16* __restrict__ w1t,
    const int4* __restrict__ tiles, const int* __restrict__ ntiles,
    float* __restrict__ out_gelu, u16* __restrict__ gb,
    const float* __restrict__ w2, u16* __restrict__ w2t){
  __shared__ __align__(16) u16 sh[2 * 128 * 64];   // 32 KB union
  int bid = blockIdx.x;
  if (bid < 32 * MAXTILES){
    gemm_body<F_DIM, H_DIM, 16, true>(sh, sh + 8192, xg, w1t, tiles, ntiles,
                                      out_gelu, gb, 0, bid & 31, bid >> 5, 0);
  } else {
    int tb = bid - 32 * MAXTILES;       // 8192 blocks: w2 [E][4096][1024] -> w2t
    transpose_body<F_DIM, H_DIM>(w2, w2t, tb & 15, (tb >> 4) & 63, tb >> 10,
                                 (u16(*)[66])sh);
  }
}

// ---------------- GEMM2 standalone (split-K=4) ----------------
__global__ __launch_bounds__(256, 4) void gemm2_kernel(
    const u16* __restrict__ gb, const u16* __restrict__ w2t,
    const int4* __restrict__ tiles, const int* __restrict__ ntiles,
    float* __restrict__ ypart){
  __shared__ __align__(16) u16 sh[2 * 128 * 64];
  gemm_body<H_DIM, F_DIM, 16, false>(sh, sh + 8192, gb, w2t, tiles, ntiles,
                                     ypart, nullptr, (size_t)M_SLOT * H_DIM,
                                     blockIdx.x, blockIdx.y, blockIdx.z);
}

// ---------------- combine: sum KSPLIT partials, weighted ----------------
__global__ __launch_bounds__(256) void combine_kernel(const float* __restrict__ yp,
                                                      const int* __restrict__ dest,
                                                      const float* __restrict__ tok_p,
                                                      float* __restrict__ out){
  int t = blockIdx.x;
  int d0 = dest[2*t], d1 = dest[2*t+1];
  float p0 = tok_p[2*t], p1 = tok_p[2*t+1];
  float4 r; r.x = 0.f; r.y = 0.f; r.z = 0.f; r.w = 0.f;
  #pragma unroll
  for (int s = 0; s < KSPLIT; s++){
    float4 a = ((const float4*)(yp + ((size_t)s * M_SLOT + d0) * H_DIM))[threadIdx.x];
    float4 b = ((const float4*)(yp + ((size_t)s * M_SLOT + d1) * H_DIM))[threadIdx.x];
    r.x += p0*a.x + p1*b.x; r.y += p0*a.y + p1*b.y;
    r.z += p0*a.z + p1*b.z; r.w += p0*a.w + p1*b.w;
  }
  ((float4*)(out + (size_t)t * H_DIM))[threadIdx.x] = r;
}

extern "C" void kernel_launch(void* const* d_in, const int* in_sizes, int n_in,
                              void* d_out, int out_size, void* d_ws, size_t ws_size,
                              hipStream_t stream) {
  const float* x  = (const float*)d_in[0];
  const float* rw = (const float*)d_in[1];
  const float* w1 = (const float*)d_in[2];
  const float* w2 = (const float*)d_in[3];
  float* out_mlp  = (float*)d_out;
  float* out_gelu = (float*)d_out + (size_t)T_TOK * H_DIM;

  char* ws = (char*)d_ws;
  // ypart [4][M][H] f32 (64 MB) aliases w1t (dead after GEMM1)
  u16*   w1t   = (u16*)(ws + 0);                 // [E][F][H] bf16, 64 MB
  float* ypart = (float*)(ws + 0);               // alias
  u16*   w2t   = (u16*)(ws + 67108864);          // [E][H][F] bf16, 64 MB
  u16*   xg    = (u16*)(ws + 134217728);         // [M+128][H] bf16
  u16*   gb    = (u16*)(ws + 143130624);         // [M+128][F] bf16
  char*  small = ws + 178782208;
  int*   tok_e = (int*)(small);
  float* tok_p = (float*)(small + 16384);
  int*   dest  = (int*)(small + 32768);
  int4*  tiles = (int4*)(small + 53248);
  int*   ntiles = (int*)(small + 54272);

  // router + w1-transpose fused (w1 streams during otherwise-idle window)
  router_tw1_kernel<<<T_TOK/4 + 8192, 256, 0, stream>>>(x, rw, tok_e, tok_p, w1, w1t);
  // hist + scan + scatter in one block
  route_pack_kernel<<<1, 256, 0, stream>>>(tok_e, dest, tiles, ntiles);
  gather_kernel<<<M_SLOT, 256, 0, stream>>>(x, dest, xg);
  // GEMM1 + transpose-w2 fused (tw2 streams in GEMM1's BW headroom)
  gemm1_tw2_kernel<<<32 * MAXTILES + 8192, 256, 0, stream>>>(
      xg, w1t, tiles, ntiles, out_gelu, gb, w2, w2t);
  // GEMM2: [M,4096] @ w2t, split-K=4
  gemm2_kernel<<<dim3(H_DIM/128, MAXTILES, KSPLIT), 256, 0, stream>>>(
      gb, w2t, tiles, ntiles, ypart);
  combine_kernel<<<T_TOK, 256, 0, stream>>>(ypart, dest, tok_p, out_mlp);
}

// Round 13
// 226.072 us; speedup vs baseline: 1.0441x; 1.0441x over previous
//
#include <hip/hip_runtime.h>
#include <hip/hip_bf16.h>
#include <stdint.h>

typedef unsigned short u16;
typedef unsigned int u32;
typedef __attribute__((ext_vector_type(8))) short short8;
typedef __attribute__((ext_vector_type(4))) float f32x4;

#define T_TOK 2048
#define H_DIM 1024
#define F_DIM 4096
#define E_NUM 8
#define M_SLOT 4096
#define MAXTILES 40
#define KSPLIT 4

__device__ __forceinline__ u16 f2bf(float f){
  union { float f; u32 u; } v; v.f = f;
  return (u16)((v.u + 0x7FFFu + ((v.u >> 16) & 1u)) >> 16);
}
__device__ __forceinline__ float bf2f(u16 b){
  union { u32 u; float f; } v; v.u = ((u32)b) << 16; return v.f;
}

__device__ __forceinline__ void gload_lds16(const void* g, void* l){
  __builtin_amdgcn_global_load_lds(
      (const __attribute__((address_space(1))) u32*)g,
      (__attribute__((address_space(3))) u32*)l, 16, 0, 0);
}

// ---------------- transpose body: [E][R][C] f32 -> [E][C][R] bf16 ----------------
template<int R, int C>
__device__ __forceinline__ void transpose_body(const float* __restrict__ in,
                                               u16* __restrict__ out,
                                               int cx, int ry, int e,
                                               u16 (*tile)[66]){
  const float* ip = in + (size_t)e * R * C;
  u16* op = out + (size_t)e * R * C;
  int c0 = cx * 64, r0 = ry * 64;
  int tr = threadIdx.x >> 4, tc = threadIdx.x & 15;
  #pragma unroll
  for (int i = 0; i < 4; i++){
    int r = tr + i * 16;
    float4 v = *(const float4*)(ip + (size_t)(r0 + r) * C + c0 + tc * 4);
    tile[r][tc*4+0] = f2bf(v.x); tile[r][tc*4+1] = f2bf(v.y);
    tile[r][tc*4+2] = f2bf(v.z); tile[r][tc*4+3] = f2bf(v.w);
  }
  __syncthreads();
  #pragma unroll
  for (int i = 0; i < 4; i++){
    int c = tr + i * 16;
    ushort4 o;
    o.x = tile[tc*4+0][c]; o.y = tile[tc*4+1][c];
    o.z = tile[tc*4+2][c]; o.w = tile[tc*4+3][c];
    *(ushort4*)(op + (size_t)(c0 + c) * R + r0 + tc * 4) = o;
  }
}

// ---------------- fused: router (512 blocks) + transpose-w1 (8192 blocks) ----
__global__ __launch_bounds__(256) void router_tw1_kernel(
    const float* __restrict__ x, const float* __restrict__ rw,
    int* __restrict__ tok_e, float* __restrict__ tok_p,
    const float* __restrict__ w1, u16* __restrict__ w1t){
  __shared__ __align__(16) char shbuf[E_NUM * H_DIM * 4];   // 32 KB union
  int bid = blockIdx.x;
  if (bid >= T_TOK / 4){
    int tb = bid - T_TOK / 4;        // 8192 blocks: w1 [E][1024][4096] -> w1t
    transpose_body<H_DIM, F_DIM>(w1, w1t, tb & 63, (tb >> 6) & 15, tb >> 10,
                                 (u16(*)[66])shbuf);
    return;
  }
  float* wlds = (float*)shbuf;
  int tid = threadIdx.x;
  for (int i = tid; i < H_DIM * E_NUM; i += 256){
    int h = i >> 3, e = i & 7;
    wlds[e * H_DIM + h] = rw[i];
  }
  __syncthreads();
  int wave = tid >> 6, lane = tid & 63;
  int t = bid * 4 + wave;
  const float* xr = x + (size_t)t * H_DIM;
  float acc[E_NUM];
  #pragma unroll
  for (int e = 0; e < E_NUM; e++) acc[e] = 0.f;
  for (int i = 0; i < H_DIM / 64; i++){
    float xv = xr[lane + 64 * i];
    #pragma unroll
    for (int e = 0; e < E_NUM; e++) acc[e] += xv * wlds[e * H_DIM + lane + 64 * i];
  }
  #pragma unroll
  for (int e = 0; e < E_NUM; e++){
    float r = acc[e];
    #pragma unroll
    for (int off = 32; off; off >>= 1) r += __shfl_xor(r, off, 64);
    acc[e] = r;
  }
  if (lane == 0){
    float l0 = acc[0]; int e0 = 0;
    #pragma unroll
    for (int e = 1; e < E_NUM; e++) if (acc[e] > l0){ l0 = acc[e]; e0 = e; }
    float l1 = -INFINITY; int e1 = 0;
    #pragma unroll
    for (int e = 0; e < E_NUM; e++) if (e != e0 && acc[e] > l1){ l1 = acc[e]; e1 = e; }
    float ex = expf(l1 - l0);
    float inv = 1.f / (1.f + ex);
    tok_e[2*t] = e0; tok_e[2*t+1] = e1;
    tok_p[2*t] = inv; tok_p[2*t+1] = ex * inv;
  }
}

// ---------------- fused hist+scan+scatter: ONE block, 256 threads ----------
__global__ __launch_bounds__(256) void route_pack_kernel(
    const int* __restrict__ tok_e, int* __restrict__ dest,
    int4* __restrict__ tiles, int* __restrict__ ntiles){
  __shared__ u32 part[64][E_NUM];
  __shared__ u32 base[64][E_NUM];
  int tid = threadIdx.x, lane = tid & 63, wv = tid >> 6;
  for (int c = wv; c < 64; c += 4){
    int e = tok_e[c * 64 + lane];
    #pragma unroll
    for (int ee = 0; ee < E_NUM; ee++){
      unsigned long long mk = __ballot(e == ee);
      if (lane == ee) part[c][ee] = (u32)__popcll(mk);
    }
  }
  __syncthreads();
  if (wv == 0){
    u32 exc[E_NUM], tot[E_NUM];
    #pragma unroll
    for (int e = 0; e < E_NUM; e++){
      u32 v = part[lane][e];
      u32 own = v;
      #pragma unroll
      for (int off = 1; off < 64; off <<= 1){
        u32 tu = __shfl_up(v, off, 64);
        if (lane >= off) v += tu;
      }
      exc[e] = v - own;
      tot[e] = __shfl(v, 63, 64);
    }
    u32 offs[E_NUM + 1]; offs[0] = 0;
    #pragma unroll
    for (int e = 0; e < E_NUM; e++) offs[e+1] = offs[e] + tot[e];
    #pragma unroll
    for (int e = 0; e < E_NUM; e++) base[lane][e] = offs[e] + exc[e];
    if (lane == 0){
      int nt = 0;
      for (int e = 0; e < E_NUM; e++){
        int cnt = (int)tot[e];
        for (int r0 = 0; r0 < cnt; r0 += 128){
          tiles[nt] = make_int4((int)offs[e] + r0, min(128, cnt - r0), e, 0);
          nt++;
        }
      }
      *ntiles = nt;
    }
  }
  __syncthreads();
  for (int c = wv; c < 64; c += 4){
    int e = tok_e[c * 64 + lane];
    unsigned long long eq = 0;
    #pragma unroll
    for (int ee = 0; ee < E_NUM; ee++){
      unsigned long long mk = __ballot(e == ee);
      if (e == ee) eq = mk;
    }
    u32 rank = (u32)__popcll(eq & ((1ull << lane) - 1ull));
    dest[c * 64 + lane] = (int)(base[c][e] + rank);
  }
}

// ---------------- gather x rows -> grouped bf16 ----------------
__global__ __launch_bounds__(256) void gather_kernel(const float* __restrict__ x,
                                                     const int* __restrict__ dest,
                                                     u16* __restrict__ xg){
  int m = blockIdx.x;
  int d = dest[m];
  const float4* xr = (const float4*)(x + (size_t)(m >> 1) * H_DIM);
  float4 v = xr[threadIdx.x];
  ushort4 o;
  o.x = f2bf(v.x); o.y = f2bf(v.y); o.z = f2bf(v.z); o.w = f2bf(v.w);
  ((ushort4*)(xg + (size_t)d * H_DIM))[threadIdx.x] = o;
}

// ---------------- gemm97 body (r5 proven): 128x128, BK=64, 4 waves ----------
// OMODE: 0 = f32 out; 1 = GELU dual (f32 + bf16); 2 = bf16 out (split-K partial)
template<int N, int KSTRIDE, int NT, int OMODE>
__device__ __forceinline__ void gemm_body(
    u16* As, u16* Bs,
    const u16* __restrict__ A, const u16* __restrict__ Bt,
    const int4* __restrict__ tiles, const int* __restrict__ ntiles_p,
    void* outP, u16* __restrict__ outB, size_t zstride,
    int colBlk, int tileBlk, int z){
  if (tileBlk >= *ntiles_p) return;
  int4 ti = tiles[tileBlk];
  int row0 = ti.x, nrows = ti.y, e = ti.z;
  int col0 = colBlk * 128;
  size_t kofs = (size_t)z * ((size_t)NT * 64);
  const u16* Be = Bt + (size_t)e * N * KSTRIDE;

  int lane = threadIdx.x & 63, wid = threadIdx.x >> 6;
  int wr = wid >> 1, wc = wid & 1;

  f32x4 acc[4][4];
  #pragma unroll
  for (int m = 0; m < 4; m++)
    #pragma unroll
    for (int n = 0; n < 4; n++) acc[m][n] = (f32x4)0.f;

  int srow = (wid << 3) + (lane >> 3);
  int skx  = ((lane & 7) * 16) ^ ((lane >> 3) << 4);

  for (int kt = 0; kt < NT; kt++){
    size_t kb = kofs + (size_t)kt * 64;
    #pragma unroll
    for (int i = 0; i < 4; i++){
      int row = i * 32 + srow;
      gload_lds16((const char*)(A  + (size_t)(row0 + row) * KSTRIDE + kb) + skx,
                  As + i * 2048 + wid * 512);
      gload_lds16((const char*)(Be + (size_t)(col0 + row) * KSTRIDE + kb) + skx,
                  Bs + i * 2048 + wid * 512);
    }
    __syncthreads();
    short8 a[4][2], b[4][2];
    #pragma unroll
    for (int m = 0; m < 4; m++){
      int row = wr * 64 + m * 16 + (lane & 15);
      #pragma unroll
      for (int kk = 0; kk < 2; kk++){
        int byte_ = row * 128 + ((kk * 64 + (lane >> 4) * 16) ^ ((row & 7) << 4));
        a[m][kk] = *(const short8*)((const char*)As + byte_);
      }
    }
    #pragma unroll
    for (int n = 0; n < 4; n++){
      int row = wc * 64 + n * 16 + (lane & 15);
      #pragma unroll
      for (int kk = 0; kk < 2; kk++){
        int byte_ = row * 128 + ((kk * 64 + (lane >> 4) * 16) ^ ((row & 7) << 4));
        b[n][kk] = *(const short8*)((const char*)Bs + byte_);
      }
    }
    #pragma unroll
    for (int m = 0; m < 4; m++)
      #pragma unroll
      for (int n = 0; n < 4; n++)
        #pragma unroll
        for (int kk = 0; kk < 2; kk++)
          acc[m][n] = __builtin_amdgcn_mfma_f32_16x16x32_bf16(a[m][kk], b[n][kk], acc[m][n], 0, 0, 0);
    __syncthreads();
  }

  #pragma unroll
  for (int m = 0; m < 4; m++){
    int rloc = wr * 64 + m * 16 + (lane >> 4) * 4;
    #pragma unroll
    for (int j = 0; j < 4; j++){
      int rr = rloc + j;
      if (rr < nrows){
        size_t rowg = (size_t)(row0 + rr);
        #pragma unroll
        for (int n = 0; n < 4; n++){
          int cc = col0 + wc * 64 + n * 16 + (lane & 15);
          float v = acc[m][n][j];
          if (OMODE == 1){
            float g = v * 0.5f * (1.f + erff(v * 0.70710678118f));
            ((float*)outP)[rowg * N + cc] = g;
            outB[rowg * N + cc] = f2bf(g);
          } else if (OMODE == 2){
            ((u16*)outP)[(size_t)z * zstride + rowg * N + cc] = f2bf(v);
          } else {
            ((float*)outP)[(size_t)z * zstride + rowg * N + cc] = v;
          }
        }
      }
    }
  }
}

// ---------------- fused: GEMM1 (bid<1280, XCD-swizzled) + transpose-w2 ----
__global__ __launch_bounds__(256, 4) void gemm1_tw2_kernel(
    const u16* __restrict__ xg, const u16* __restrict__ w1t,
    const int4* __restrict__ tiles, const int* __restrict__ ntiles,
    float* __restrict__ out_gelu, u16* __restrict__ gb,
    const float* __restrict__ w2, u16* __restrict__ w2t){
  __shared__ __align__(16) u16 sh[2 * 128 * 64];   // 32 KB union
  int bid = blockIdx.x;
  if (bid < 32 * MAXTILES){
    // T1 bijective XCD swizzle (1280 % 8 == 0): chunk 160 work items per XCD
    // -> the 32 col-blocks of each A-panel land on ONE XCD's L2.
    int w = (bid & 7) * 160 + (bid >> 3);
    gemm_body<F_DIM, H_DIM, 16, 1>(sh, sh + 8192, xg, w1t, tiles, ntiles,
                                   out_gelu, gb, 0, w & 31, w >> 5, 0);
  } else {
    int tb = bid - 32 * MAXTILES;       // 8192 blocks: w2 [E][4096][1024] -> w2t
    transpose_body<F_DIM, H_DIM>(w2, w2t, tb & 15, (tb >> 4) & 63, tb >> 10,
                                 (u16(*)[66])sh);
  }
}

// ---------------- GEMM2 (1-D grid, XCD-swizzled, split-K=4, bf16 partials) ----
__global__ __launch_bounds__(256, 4) void gemm2_kernel(
    const u16* __restrict__ gb, const u16* __restrict__ w2t,
    const int4* __restrict__ tiles, const int* __restrict__ ntiles,
    u16* __restrict__ ypart){
  __shared__ __align__(16) u16 sh[2 * 128 * 64];
  int bid = blockIdx.x;                  // 1280 = 8 cols x 40 tiles x 4 z
  int w = (bid & 7) * 160 + (bid >> 3);  // bijective XCD chunking
  int col = w & 7;
  int tz  = w >> 3;                      // 0..159 = tile + 40*z
  int tile = tz % MAXTILES, z = tz / MAXTILES;
  gemm_body<H_DIM, F_DIM, 16, 2>(sh, sh + 8192, gb, w2t, tiles, ntiles,
                                 ypart, nullptr, (size_t)M_SLOT * H_DIM,
                                 col, tile, z);
}

// ---------------- combine: sum KSPLIT bf16 partials, weighted ----------------
__global__ __launch_bounds__(256) void combine_kernel(const u16* __restrict__ yp,
                                                      const int* __restrict__ dest,
                                                      const float* __restrict__ tok_p,
                                                      float* __restrict__ out){
  int t = blockIdx.x;
  int d0 = dest[2*t], d1 = dest[2*t+1];
  float p0 = tok_p[2*t], p1 = tok_p[2*t+1];
  float4 r; r.x = 0.f; r.y = 0.f; r.z = 0.f; r.w = 0.f;
  #pragma unroll
  for (int s = 0; s < KSPLIT; s++){
    ushort4 a = ((const ushort4*)(yp + ((size_t)s * M_SLOT + d0) * H_DIM))[threadIdx.x];
    ushort4 b = ((const ushort4*)(yp + ((size_t)s * M_SLOT + d1) * H_DIM))[threadIdx.x];
    r.x += p0*bf2f(a.x) + p1*bf2f(b.x); r.y += p0*bf2f(a.y) + p1*bf2f(b.y);
    r.z += p0*bf2f(a.z) + p1*bf2f(b.z); r.w += p0*bf2f(a.w) + p1*bf2f(b.w);
  }
  ((float4*)(out + (size_t)t * H_DIM))[threadIdx.x] = r;
}

extern "C" void kernel_launch(void* const* d_in, const int* in_sizes, int n_in,
                              void* d_out, int out_size, void* d_ws, size_t ws_size,
                              hipStream_t stream) {
  const float* x  = (const float*)d_in[0];
  const float* rw = (const float*)d_in[1];
  const float* w1 = (const float*)d_in[2];
  const float* w2 = (const float*)d_in[3];
  float* out_mlp  = (float*)d_out;
  float* out_gelu = (float*)d_out + (size_t)T_TOK * H_DIM;

  char* ws = (char*)d_ws;
  // ypart [4][M][H] bf16 (32 MB) aliases w1t (dead after GEMM1)
  u16*   w1t   = (u16*)(ws + 0);                 // [E][F][H] bf16, 64 MB
  u16*   ypart = (u16*)(ws + 0);                 // alias
  u16*   w2t   = (u16*)(ws + 67108864);          // [E][H][F] bf16, 64 MB
  u16*   xg    = (u16*)(ws + 134217728);         // [M+128][H] bf16
  u16*   gb    = (u16*)(ws + 143130624);         // [M+128][F] bf16
  char*  small = ws + 178782208;
  int*   tok_e = (int*)(small);
  float* tok_p = (float*)(small + 16384);
  int*   dest  = (int*)(small + 32768);
  int4*  tiles = (int4*)(small + 53248);
  int*   ntiles = (int*)(small + 54272);

  router_tw1_kernel<<<T_TOK/4 + 8192, 256, 0, stream>>>(x, rw, tok_e, tok_p, w1, w1t);
  route_pack_kernel<<<1, 256, 0, stream>>>(tok_e, dest, tiles, ntiles);
  gather_kernel<<<M_SLOT, 256, 0, stream>>>(x, dest, xg);
  gemm1_tw2_kernel<<<32 * MAXTILES + 8192, 256, 0, stream>>>(
      xg, w1t, tiles, ntiles, out_gelu, gb, w2, w2t);
  gemm2_kernel<<<8 * MAXTILES * KSPLIT, 256, 0, stream>>>(
      gb, w2t, tiles, ntiles, ypart);
  combine_kernel<<<T_TOK, 256, 0, stream>>>(ypart, dest, tok_p, out_mlp);
}

// Round 14
// 225.272 us; speedup vs baseline: 1.0478x; 1.0036x over previous
//
#include <hip/hip_runtime.h>
#include <hip/hip_bf16.h>
#include <stdint.h>

typedef unsigned short u16;
typedef unsigned int u32;
typedef __attribute__((ext_vector_type(8))) short short8;
typedef __attribute__((ext_vector_type(4))) float f32x4;

#define T_TOK 2048
#define H_DIM 1024
#define F_DIM 4096
#define E_NUM 8
#define M_SLOT 4096
#define MAXTILES 40
#define KSPLIT 4

__device__ __forceinline__ u16 f2bf(float f){
  union { float f; u32 u; } v; v.f = f;
  return (u16)((v.u + 0x7FFFu + ((v.u >> 16) & 1u)) >> 16);
}
__device__ __forceinline__ float bf2f(u16 b){
  union { u32 u; float f; } v; v.u = ((u32)b) << 16; return v.f;
}

__device__ __forceinline__ void gload_lds16(const void* g, void* l){
  __builtin_amdgcn_global_load_lds(
      (const __attribute__((address_space(1))) u32*)g,
      (__attribute__((address_space(3))) u32*)l, 16, 0, 0);
}

// ---------------- transpose body: [E][R][C] f32 -> [E][C][R] bf16 ----------------
template<int R, int C>
__device__ __forceinline__ void transpose_body(const float* __restrict__ in,
                                               u16* __restrict__ out,
                                               int cx, int ry, int e,
                                               u16 (*tile)[66]){
  const float* ip = in + (size_t)e * R * C;
  u16* op = out + (size_t)e * R * C;
  int c0 = cx * 64, r0 = ry * 64;
  int tr = threadIdx.x >> 4, tc = threadIdx.x & 15;
  #pragma unroll
  for (int i = 0; i < 4; i++){
    int r = tr + i * 16;
    float4 v = *(const float4*)(ip + (size_t)(r0 + r) * C + c0 + tc * 4);
    tile[r][tc*4+0] = f2bf(v.x); tile[r][tc*4+1] = f2bf(v.y);
    tile[r][tc*4+2] = f2bf(v.z); tile[r][tc*4+3] = f2bf(v.w);
  }
  __syncthreads();
  #pragma unroll
  for (int i = 0; i < 4; i++){
    int c = tr + i * 16;
    ushort4 o;
    o.x = tile[tc*4+0][c]; o.y = tile[tc*4+1][c];
    o.z = tile[tc*4+2][c]; o.w = tile[tc*4+3][c];
    *(ushort4*)(op + (size_t)(c0 + c) * R + r0 + tc * 4) = o;
  }
}

// ---------------- fused: router (512 blocks) + transpose-w1 (8192 blocks) ----
__global__ __launch_bounds__(256) void router_tw1_kernel(
    const float* __restrict__ x, const float* __restrict__ rw,
    int* __restrict__ tok_e, float* __restrict__ tok_p,
    const float* __restrict__ w1, u16* __restrict__ w1t){
  __shared__ __align__(16) char shbuf[E_NUM * H_DIM * 4];   // 32 KB union
  int bid = blockIdx.x;
  if (bid >= T_TOK / 4){
    int tb = bid - T_TOK / 4;        // 8192 blocks: w1 [E][1024][4096] -> w1t
    transpose_body<H_DIM, F_DIM>(w1, w1t, tb & 63, (tb >> 6) & 15, tb >> 10,
                                 (u16(*)[66])shbuf);
    return;
  }
  float* wlds = (float*)shbuf;
  int tid = threadIdx.x;
  for (int i = tid; i < H_DIM * E_NUM; i += 256){
    int h = i >> 3, e = i & 7;
    wlds[e * H_DIM + h] = rw[i];
  }
  __syncthreads();
  int wave = tid >> 6, lane = tid & 63;
  int t = bid * 4 + wave;
  const float* xr = x + (size_t)t * H_DIM;
  float acc[E_NUM];
  #pragma unroll
  for (int e = 0; e < E_NUM; e++) acc[e] = 0.f;
  for (int i = 0; i < H_DIM / 64; i++){
    float xv = xr[lane + 64 * i];
    #pragma unroll
    for (int e = 0; e < E_NUM; e++) acc[e] += xv * wlds[e * H_DIM + lane + 64 * i];
  }
  #pragma unroll
  for (int e = 0; e < E_NUM; e++){
    float r = acc[e];
    #pragma unroll
    for (int off = 32; off; off >>= 1) r += __shfl_xor(r, off, 64);
    acc[e] = r;
  }
  if (lane == 0){
    float l0 = acc[0]; int e0 = 0;
    #pragma unroll
    for (int e = 1; e < E_NUM; e++) if (acc[e] > l0){ l0 = acc[e]; e0 = e; }
    float l1 = -INFINITY; int e1 = 0;
    #pragma unroll
    for (int e = 0; e < E_NUM; e++) if (e != e0 && acc[e] > l1){ l1 = acc[e]; e1 = e; }
    float ex = expf(l1 - l0);
    float inv = 1.f / (1.f + ex);
    tok_e[2*t] = e0; tok_e[2*t+1] = e1;
    tok_p[2*t] = inv; tok_p[2*t+1] = ex * inv;
  }
}

// ---------------- fused hist+scan+scatter: ONE block, 256 threads ----------
__global__ __launch_bounds__(256) void route_pack_kernel(
    const int* __restrict__ tok_e, int* __restrict__ dest,
    int4* __restrict__ tiles, int* __restrict__ ntiles){
  __shared__ u32 part[64][E_NUM];
  __shared__ u32 base[64][E_NUM];
  int tid = threadIdx.x, lane = tid & 63, wv = tid >> 6;
  for (int c = wv; c < 64; c += 4){
    int e = tok_e[c * 64 + lane];
    #pragma unroll
    for (int ee = 0; ee < E_NUM; ee++){
      unsigned long long mk = __ballot(e == ee);
      if (lane == ee) part[c][ee] = (u32)__popcll(mk);
    }
  }
  __syncthreads();
  if (wv == 0){
    u32 exc[E_NUM], tot[E_NUM];
    #pragma unroll
    for (int e = 0; e < E_NUM; e++){
      u32 v = part[lane][e];
      u32 own = v;
      #pragma unroll
      for (int off = 1; off < 64; off <<= 1){
        u32 tu = __shfl_up(v, off, 64);
        if (lane >= off) v += tu;
      }
      exc[e] = v - own;
      tot[e] = __shfl(v, 63, 64);
    }
    u32 offs[E_NUM + 1]; offs[0] = 0;
    #pragma unroll
    for (int e = 0; e < E_NUM; e++) offs[e+1] = offs[e] + tot[e];
    #pragma unroll
    for (int e = 0; e < E_NUM; e++) base[lane][e] = offs[e] + exc[e];
    if (lane == 0){
      int nt = 0;
      for (int e = 0; e < E_NUM; e++){
        int cnt = (int)tot[e];
        for (int r0 = 0; r0 < cnt; r0 += 128){
          tiles[nt] = make_int4((int)offs[e] + r0, min(128, cnt - r0), e, 0);
          nt++;
        }
      }
      *ntiles = nt;
    }
  }
  __syncthreads();
  for (int c = wv; c < 64; c += 4){
    int e = tok_e[c * 64 + lane];
    unsigned long long eq = 0;
    #pragma unroll
    for (int ee = 0; ee < E_NUM; ee++){
      unsigned long long mk = __ballot(e == ee);
      if (e == ee) eq = mk;
    }
    u32 rank = (u32)__popcll(eq & ((1ull << lane) - 1ull));
    dest[c * 64 + lane] = (int)(base[c][e] + rank);
  }
}

// ---------------- gather x rows -> grouped bf16 ----------------
__global__ __launch_bounds__(256) void gather_kernel(const float* __restrict__ x,
                                                     const int* __restrict__ dest,
                                                     u16* __restrict__ xg){
  int m = blockIdx.x;
  int d = dest[m];
  const float4* xr = (const float4*)(x + (size_t)(m >> 1) * H_DIM);
  float4 v = xr[threadIdx.x];
  ushort4 o;
  o.x = f2bf(v.x); o.y = f2bf(v.y); o.z = f2bf(v.z); o.w = f2bf(v.w);
  ((ushort4*)(xg + (size_t)d * H_DIM))[threadIdx.x] = o;
}

// ---------------- gemm97 body (r5 proven): 128x128, BK=64, 4 waves ----------
// OMODE: 0 = f32 out; 1 = GELU dual (f32 + bf16); 2 = bf16 out (split-K partial)
template<int N, int KSTRIDE, int NT, int OMODE>
__device__ __forceinline__ void gemm_body(
    u16* As, u16* Bs,
    const u16* __restrict__ A, const u16* __restrict__ Bt,
    const int4* __restrict__ tiles, const int* __restrict__ ntiles_p,
    void* outP, u16* __restrict__ outB, size_t zstride,
    int colBlk, int tileBlk, int z){
  if (tileBlk >= *ntiles_p) return;
  int4 ti = tiles[tileBlk];
  int row0 = ti.x, nrows = ti.y, e = ti.z;
  int col0 = colBlk * 128;
  size_t kofs = (size_t)z * ((size_t)NT * 64);
  const u16* Be = Bt + (size_t)e * N * KSTRIDE;

  int lane = threadIdx.x & 63, wid = threadIdx.x >> 6;
  int wr = wid >> 1, wc = wid & 1;

  f32x4 acc[4][4];
  #pragma unroll
  for (int m = 0; m < 4; m++)
    #pragma unroll
    for (int n = 0; n < 4; n++) acc[m][n] = (f32x4)0.f;

  int srow = (wid << 3) + (lane >> 3);
  int skx  = ((lane & 7) * 16) ^ ((lane >> 3) << 4);

  for (int kt = 0; kt < NT; kt++){
    size_t kb = kofs + (size_t)kt * 64;
    #pragma unroll
    for (int i = 0; i < 4; i++){
      int row = i * 32 + srow;
      gload_lds16((const char*)(A  + (size_t)(row0 + row) * KSTRIDE + kb) + skx,
                  As + i * 2048 + wid * 512);
      gload_lds16((const char*)(Be + (size_t)(col0 + row) * KSTRIDE + kb) + skx,
                  Bs + i * 2048 + wid * 512);
    }
    __syncthreads();
    short8 a[4][2], b[4][2];
    #pragma unroll
    for (int m = 0; m < 4; m++){
      int row = wr * 64 + m * 16 + (lane & 15);
      #pragma unroll
      for (int kk = 0; kk < 2; kk++){
        int byte_ = row * 128 + ((kk * 64 + (lane >> 4) * 16) ^ ((row & 7) << 4));
        a[m][kk] = *(const short8*)((const char*)As + byte_);
      }
    }
    #pragma unroll
    for (int n = 0; n < 4; n++){
      int row = wc * 64 + n * 16 + (lane & 15);
      #pragma unroll
      for (int kk = 0; kk < 2; kk++){
        int byte_ = row * 128 + ((kk * 64 + (lane >> 4) * 16) ^ ((row & 7) << 4));
        b[n][kk] = *(const short8*)((const char*)Bs + byte_);
      }
    }
    #pragma unroll
    for (int m = 0; m < 4; m++)
      #pragma unroll
      for (int n = 0; n < 4; n++)
        #pragma unroll
        for (int kk = 0; kk < 2; kk++)
          acc[m][n] = __builtin_amdgcn_mfma_f32_16x16x32_bf16(a[m][kk], b[n][kk], acc[m][n], 0, 0, 0);
    __syncthreads();
  }

  #pragma unroll
  for (int m = 0; m < 4; m++){
    int rloc = wr * 64 + m * 16 + (lane >> 4) * 4;
    #pragma unroll
    for (int j = 0; j < 4; j++){
      int rr = rloc + j;
      if (rr < nrows){
        size_t rowg = (size_t)(row0 + rr);
        #pragma unroll
        for (int n = 0; n < 4; n++){
          int cc = col0 + wc * 64 + n * 16 + (lane & 15);
          float v = acc[m][n][j];
          if (OMODE == 1){
            float g = v * 0.5f * (1.f + erff(v * 0.70710678118f));
            ((float*)outP)[rowg * N + cc] = g;
            outB[rowg * N + cc] = f2bf(g);
          } else if (OMODE == 2){
            ((u16*)outP)[(size_t)z * zstride + rowg * N + cc] = f2bf(v);
          } else {
            ((float*)outP)[(size_t)z * zstride + rowg * N + cc] = v;
          }
        }
      }
    }
  }
}

// ---------------- fused: GEMM1 (bid<1280, identity map) + transpose-w2 ----
// NOTE r13 lesson: XCD-chunked swizzle concentrated the data-dependent
// invalid-tile guard blocks onto one XCD (ntiles ~34 < MAXTILES) -> imbalance.
// Identity mapping spreads guards evenly via round-robin dispatch.
__global__ __launch_bounds__(256, 4) void gemm1_tw2_kernel(
    const u16* __restrict__ xg, const u16* __restrict__ w1t,
    const int4* __restrict__ tiles, const int* __restrict__ ntiles,
    float* __restrict__ out_gelu, u16* __restrict__ gb,
    const float* __restrict__ w2, u16* __restrict__ w2t){
  __shared__ __align__(16) u16 sh[2 * 128 * 64];   // 32 KB union
  int bid = blockIdx.x;
  if (bid < 32 * MAXTILES){
    gemm_body<F_DIM, H_DIM, 16, 1>(sh, sh + 8192, xg, w1t, tiles, ntiles,
                                   out_gelu, gb, 0, bid & 31, bid >> 5, 0);
  } else {
    int tb = bid - 32 * MAXTILES;       // 8192 blocks: w2 [E][4096][1024] -> w2t
    transpose_body<F_DIM, H_DIM>(w2, w2t, tb & 15, (tb >> 4) & 63, tb >> 10,
                                 (u16(*)[66])sh);
  }
}

// ---------------- GEMM2 (identity map, split-K=4, bf16 partials) ----------
__global__ __launch_bounds__(256, 4) void gemm2_kernel(
    const u16* __restrict__ gb, const u16* __restrict__ w2t,
    const int4* __restrict__ tiles, const int* __restrict__ ntiles,
    u16* __restrict__ ypart){
  __shared__ __align__(16) u16 sh[2 * 128 * 64];
  gemm_body<H_DIM, F_DIM, 16, 2>(sh, sh + 8192, gb, w2t, tiles, ntiles,
                                 ypart, nullptr, (size_t)M_SLOT * H_DIM,
                                 blockIdx.x, blockIdx.y, blockIdx.z);
}

// ---------------- combine: sum KSPLIT bf16 partials, weighted ----------------
__global__ __launch_bounds__(256) void combine_kernel(const u16* __restrict__ yp,
                                                      const int* __restrict__ dest,
                                                      const float* __restrict__ tok_p,
                                                      float* __restrict__ out){
  int t = blockIdx.x;
  int d0 = dest[2*t], d1 = dest[2*t+1];
  float p0 = tok_p[2*t], p1 = tok_p[2*t+1];
  float4 r; r.x = 0.f; r.y = 0.f; r.z = 0.f; r.w = 0.f;
  #pragma unroll
  for (int s = 0; s < KSPLIT; s++){
    ushort4 a = ((const ushort4*)(yp + ((size_t)s * M_SLOT + d0) * H_DIM))[threadIdx.x];
    ushort4 b = ((const ushort4*)(yp + ((size_t)s * M_SLOT + d1) * H_DIM))[threadIdx.x];
    r.x += p0*bf2f(a.x) + p1*bf2f(b.x); r.y += p0*bf2f(a.y) + p1*bf2f(b.y);
    r.z += p0*bf2f(a.z) + p1*bf2f(b.z); r.w += p0*bf2f(a.w) + p1*bf2f(b.w);
  }
  ((float4*)(out + (size_t)t * H_DIM))[threadIdx.x] = r;
}

extern "C" void kernel_launch(void* const* d_in, const int* in_sizes, int n_in,
                              void* d_out, int out_size, void* d_ws, size_t ws_size,
                              hipStream_t stream) {
  const float* x  = (const float*)d_in[0];
  const float* rw = (const float*)d_in[1];
  const float* w1 = (const float*)d_in[2];
  const float* w2 = (const float*)d_in[3];
  float* out_mlp  = (float*)d_out;
  float* out_gelu = (float*)d_out + (size_t)T_TOK * H_DIM;

  char* ws = (char*)d_ws;
  // ypart [4][M][H] bf16 (32 MB) aliases w1t (dead after GEMM1)
  u16*   w1t   = (u16*)(ws + 0);                 // [E][F][H] bf16, 64 MB
  u16*   ypart = (u16*)(ws + 0);                 // alias
  u16*   w2t   = (u16*)(ws + 67108864);          // [E][H][F] bf16, 64 MB
  u16*   xg    = (u16*)(ws + 134217728);         // [M+128][H] bf16
  u16*   gb    = (u16*)(ws + 143130624);         // [M+128][F] bf16
  char*  small = ws + 178782208;
  int*   tok_e = (int*)(small);
  float* tok_p = (float*)(small + 16384);
  int*   dest  = (int*)(small + 32768);
  int4*  tiles = (int4*)(small + 53248);
  int*   ntiles = (int*)(small + 54272);

  router_tw1_kernel<<<T_TOK/4 + 8192, 256, 0, stream>>>(x, rw, tok_e, tok_p, w1, w1t);
  route_pack_kernel<<<1, 256, 0, stream>>>(tok_e, dest, tiles, ntiles);
  gather_kernel<<<M_SLOT, 256, 0, stream>>>(x, dest, xg);
  gemm1_tw2_kernel<<<32 * MAXTILES + 8192, 256, 0, stream>>>(
      xg, w1t, tiles, ntiles, out_gelu, gb, w2, w2t);
  gemm2_kernel<<<dim3(H_DIM/128, MAXTILES, KSPLIT), 256, 0, stream>>>(
      gb, w2t, tiles, ntiles, ypart);
  combine_kernel<<<T_TOK, 256, 0, stream>>>(ypart, dest, tok_p, out_mlp);
}

// Round 15
// 222.046 us; speedup vs baseline: 1.0630x; 1.0145x over previous
//
#include <hip/hip_runtime.h>
#include <hip/hip_bf16.h>
#include <stdint.h>

typedef unsigned short u16;
typedef unsigned int u32;
typedef __attribute__((ext_vector_type(8))) short short8;
typedef __attribute__((ext_vector_type(4))) float f32x4;

#define T_TOK 2048
#define H_DIM 1024
#define F_DIM 4096
#define E_NUM 8
#define M_SLOT 4096
#define MAXTILES 40
#define KSPLIT 4

__device__ __forceinline__ u16 f2bf(float f){
  union { float f; u32 u; } v; v.f = f;
  return (u16)((v.u + 0x7FFFu + ((v.u >> 16) & 1u)) >> 16);
}
__device__ __forceinline__ float bf2f(u16 b){
  union { u32 u; float f; } v; v.u = ((u32)b) << 16; return v.f;
}

__device__ __forceinline__ void gload_lds16(const void* g, void* l){
  __builtin_amdgcn_global_load_lds(
      (const __attribute__((address_space(1))) u32*)g,
      (__attribute__((address_space(3))) u32*)l, 16, 0, 0);
}

// m204 bijective XCD chunking over [0, nwork): XCD k = bid&7 gets a
// CONTIGUOUS chunk of work items. Valid for bid < nwork, any nwork.
__device__ __forceinline__ int xcd_chunk(int bid, int nwork){
  int q = nwork >> 3, r = nwork & 7;
  int xcd = bid & 7, idx = bid >> 3;
  return (xcd < r) ? xcd * (q + 1) + idx : r * (q + 1) + (xcd - r) * q + idx;
}

// ---------------- transpose body: [E][R][C] f32 -> [E][C][R] bf16 ----------------
template<int R, int C>
__device__ __forceinline__ void transpose_body(const float* __restrict__ in,
                                               u16* __restrict__ out,
                                               int cx, int ry, int e,
                                               u16 (*tile)[66]){
  const float* ip = in + (size_t)e * R * C;
  u16* op = out + (size_t)e * R * C;
  int c0 = cx * 64, r0 = ry * 64;
  int tr = threadIdx.x >> 4, tc = threadIdx.x & 15;
  #pragma unroll
  for (int i = 0; i < 4; i++){
    int r = tr + i * 16;
    float4 v = *(const float4*)(ip + (size_t)(r0 + r) * C + c0 + tc * 4);
    tile[r][tc*4+0] = f2bf(v.x); tile[r][tc*4+1] = f2bf(v.y);
    tile[r][tc*4+2] = f2bf(v.z); tile[r][tc*4+3] = f2bf(v.w);
  }
  __syncthreads();
  #pragma unroll
  for (int i = 0; i < 4; i++){
    int c = tr + i * 16;
    ushort4 o;
    o.x = tile[tc*4+0][c]; o.y = tile[tc*4+1][c];
    o.z = tile[tc*4+2][c]; o.w = tile[tc*4+3][c];
    *(ushort4*)(op + (size_t)(c0 + c) * R + r0 + tc * 4) = o;
  }
}

// ---------------- fused: router (512 blocks) + transpose-w1 (8192 blocks) ----
__global__ __launch_bounds__(256) void router_tw1_kernel(
    const float* __restrict__ x, const float* __restrict__ rw,
    int* __restrict__ tok_e, float* __restrict__ tok_p,
    const float* __restrict__ w1, u16* __restrict__ w1t){
  __shared__ __align__(16) char shbuf[E_NUM * H_DIM * 4];   // 32 KB union
  int bid = blockIdx.x;
  if (bid >= T_TOK / 4){
    int tb = bid - T_TOK / 4;        // 8192 blocks: w1 [E][1024][4096] -> w1t
    transpose_body<H_DIM, F_DIM>(w1, w1t, tb & 63, (tb >> 6) & 15, tb >> 10,
                                 (u16(*)[66])shbuf);
    return;
  }
  float* wlds = (float*)shbuf;
  int tid = threadIdx.x;
  for (int i = tid; i < H_DIM * E_NUM; i += 256){
    int h = i >> 3, e = i & 7;
    wlds[e * H_DIM + h] = rw[i];
  }
  __syncthreads();
  int wave = tid >> 6, lane = tid & 63;
  int t = bid * 4 + wave;
  const float* xr = x + (size_t)t * H_DIM;
  float acc[E_NUM];
  #pragma unroll
  for (int e = 0; e < E_NUM; e++) acc[e] = 0.f;
  for (int i = 0; i < H_DIM / 64; i++){
    float xv = xr[lane + 64 * i];
    #pragma unroll
    for (int e = 0; e < E_NUM; e++) acc[e] += xv * wlds[e * H_DIM + lane + 64 * i];
  }
  #pragma unroll
  for (int e = 0; e < E_NUM; e++){
    float r = acc[e];
    #pragma unroll
    for (int off = 32; off; off >>= 1) r += __shfl_xor(r, off, 64);
    acc[e] = r;
  }
  if (lane == 0){
    float l0 = acc[0]; int e0 = 0;
    #pragma unroll
    for (int e = 1; e < E_NUM; e++) if (acc[e] > l0){ l0 = acc[e]; e0 = e; }
    float l1 = -INFINITY; int e1 = 0;
    #pragma unroll
    for (int e = 0; e < E_NUM; e++) if (e != e0 && acc[e] > l1){ l1 = acc[e]; e1 = e; }
    float ex = expf(l1 - l0);
    float inv = 1.f / (1.f + ex);
    tok_e[2*t] = e0; tok_e[2*t+1] = e1;
    tok_p[2*t] = inv; tok_p[2*t+1] = ex * inv;
  }
}

// ---------------- fused hist+scan+scatter: ONE block, 256 threads ----------
__global__ __launch_bounds__(256) void route_pack_kernel(
    const int* __restrict__ tok_e, int* __restrict__ dest,
    int4* __restrict__ tiles, int* __restrict__ ntiles){
  __shared__ u32 part[64][E_NUM];
  __shared__ u32 base[64][E_NUM];
  int tid = threadIdx.x, lane = tid & 63, wv = tid >> 6;
  for (int c = wv; c < 64; c += 4){
    int e = tok_e[c * 64 + lane];
    #pragma unroll
    for (int ee = 0; ee < E_NUM; ee++){
      unsigned long long mk = __ballot(e == ee);
      if (lane == ee) part[c][ee] = (u32)__popcll(mk);
    }
  }
  __syncthreads();
  if (wv == 0){
    u32 exc[E_NUM], tot[E_NUM];
    #pragma unroll
    for (int e = 0; e < E_NUM; e++){
      u32 v = part[lane][e];
      u32 own = v;
      #pragma unroll
      for (int off = 1; off < 64; off <<= 1){
        u32 tu = __shfl_up(v, off, 64);
        if (lane >= off) v += tu;
      }
      exc[e] = v - own;
      tot[e] = __shfl(v, 63, 64);
    }
    u32 offs[E_NUM + 1]; offs[0] = 0;
    #pragma unroll
    for (int e = 0; e < E_NUM; e++) offs[e+1] = offs[e] + tot[e];
    #pragma unroll
    for (int e = 0; e < E_NUM; e++) base[lane][e] = offs[e] + exc[e];
    if (lane == 0){
      int nt = 0;
      for (int e = 0; e < E_NUM; e++){
        int cnt = (int)tot[e];
        for (int r0 = 0; r0 < cnt; r0 += 128){
          tiles[nt] = make_int4((int)offs[e] + r0, min(128, cnt - r0), e, 0);
          nt++;
        }
      }
      *ntiles = nt;
    }
  }
  __syncthreads();
  for (int c = wv; c < 64; c += 4){
    int e = tok_e[c * 64 + lane];
    unsigned long long eq = 0;
    #pragma unroll
    for (int ee = 0; ee < E_NUM; ee++){
      unsigned long long mk = __ballot(e == ee);
      if (e == ee) eq = mk;
    }
    u32 rank = (u32)__popcll(eq & ((1ull << lane) - 1ull));
    dest[c * 64 + lane] = (int)(base[c][e] + rank);
  }
}

// ---------------- gather x rows -> grouped bf16 ----------------
__global__ __launch_bounds__(256) void gather_kernel(const float* __restrict__ x,
                                                     const int* __restrict__ dest,
                                                     u16* __restrict__ xg){
  int m = blockIdx.x;
  int d = dest[m];
  const float4* xr = (const float4*)(x + (size_t)(m >> 1) * H_DIM);
  float4 v = xr[threadIdx.x];
  ushort4 o;
  o.x = f2bf(v.x); o.y = f2bf(v.y); o.z = f2bf(v.z); o.w = f2bf(v.w);
  ((ushort4*)(xg + (size_t)d * H_DIM))[threadIdx.x] = o;
}

// ---------------- gemm97 body (r5 proven): 128x128, BK=64, 4 waves ----------
// OMODE: 1 = GELU dual (f32 + bf16); 2 = bf16 out (split-K partial)
template<int N, int KSTRIDE, int NT, int OMODE>
__device__ __forceinline__ void gemm_body(
    u16* As, u16* Bs,
    const u16* __restrict__ A, const u16* __restrict__ Bt,
    const int4* __restrict__ tiles,
    void* outP, u16* __restrict__ outB, size_t zstride,
    int colBlk, int tileBlk, int z){
  int4 ti = tiles[tileBlk];
  int row0 = ti.x, nrows = ti.y, e = ti.z;
  int col0 = colBlk * 128;
  size_t kofs = (size_t)z * ((size_t)NT * 64);
  const u16* Be = Bt + (size_t)e * N * KSTRIDE;

  int lane = threadIdx.x & 63, wid = threadIdx.x >> 6;
  int wr = wid >> 1, wc = wid & 1;

  f32x4 acc[4][4];
  #pragma unroll
  for (int m = 0; m < 4; m++)
    #pragma unroll
    for (int n = 0; n < 4; n++) acc[m][n] = (f32x4)0.f;

  int srow = (wid << 3) + (lane >> 3);
  int skx  = ((lane & 7) * 16) ^ ((lane >> 3) << 4);

  for (int kt = 0; kt < NT; kt++){
    size_t kb = kofs + (size_t)kt * 64;
    #pragma unroll
    for (int i = 0; i < 4; i++){
      int row = i * 32 + srow;
      gload_lds16((const char*)(A  + (size_t)(row0 + row) * KSTRIDE + kb) + skx,
                  As + i * 2048 + wid * 512);
      gload_lds16((const char*)(Be + (size_t)(col0 + row) * KSTRIDE + kb) + skx,
                  Bs + i * 2048 + wid * 512);
    }
    __syncthreads();
    short8 a[4][2], b[4][2];
    #pragma unroll
    for (int m = 0; m < 4; m++){
      int row = wr * 64 + m * 16 + (lane & 15);
      #pragma unroll
      for (int kk = 0; kk < 2; kk++){
        int byte_ = row * 128 + ((kk * 64 + (lane >> 4) * 16) ^ ((row & 7) << 4));
        a[m][kk] = *(const short8*)((const char*)As + byte_);
      }
    }
    #pragma unroll
    for (int n = 0; n < 4; n++){
      int row = wc * 64 + n * 16 + (lane & 15);
      #pragma unroll
      for (int kk = 0; kk < 2; kk++){
        int byte_ = row * 128 + ((kk * 64 + (lane >> 4) * 16) ^ ((row & 7) << 4));
        b[n][kk] = *(const short8*)((const char*)Bs + byte_);
      }
    }
    #pragma unroll
    for (int m = 0; m < 4; m++)
      #pragma unroll
      for (int n = 0; n < 4; n++)
        #pragma unroll
        for (int kk = 0; kk < 2; kk++)
          acc[m][n] = __builtin_amdgcn_mfma_f32_16x16x32_bf16(a[m][kk], b[n][kk], acc[m][n], 0, 0, 0);
    __syncthreads();
  }

  #pragma unroll
  for (int m = 0; m < 4; m++){
    int rloc = wr * 64 + m * 16 + (lane >> 4) * 4;
    #pragma unroll
    for (int j = 0; j < 4; j++){
      int rr = rloc + j;
      if (rr < nrows){
        size_t rowg = (size_t)(row0 + rr);
        #pragma unroll
        for (int n = 0; n < 4; n++){
          int cc = col0 + wc * 64 + n * 16 + (lane & 15);
          float v = acc[m][n][j];
          if (OMODE == 1){
            float g = v * 0.5f * (1.f + erff(v * 0.70710678118f));
            ((float*)outP)[rowg * N + cc] = g;
            outB[rowg * N + cc] = f2bf(g);
          } else {
            ((u16*)outP)[(size_t)z * zstride + rowg * N + cc] = f2bf(v);
          }
        }
      }
    }
  }
}

// ---------------- fused: GEMM1 (guard-aware XCD swizzle) + transpose-w2 ----
// r13/r14 lesson: chunked swizzle over the FULL padded grid concentrates the
// data-dependent guard blocks on one XCD. Fix: read ntiles, exit guards
// (bid >= nwork, round-robin spread = balanced), bijective-chunk the VALID
// range only -> each XCD gets contiguous (tile,col) work sharing A-panels in
// its L2.
__global__ __launch_bounds__(256, 4) void gemm1_tw2_kernel(
    const u16* __restrict__ xg, const u16* __restrict__ w1t,
    const int4* __restrict__ tiles, const int* __restrict__ ntiles,
    float* __restrict__ out_gelu, u16* __restrict__ gb,
    const float* __restrict__ w2, u16* __restrict__ w2t){
  __shared__ __align__(16) u16 sh[2 * 128 * 64];   // 32 KB union
  int bid = blockIdx.x;
  if (bid < 32 * MAXTILES){
    int nwork = *ntiles * 32;
    if (bid >= nwork) return;                  // guards spread round-robin
    int w = xcd_chunk(bid, nwork);             // col fastest: A-panel reuse
    gemm_body<F_DIM, H_DIM, 16, 1>(sh, sh + 8192, xg, w1t, tiles,
                                   out_gelu, gb, 0, w & 31, w >> 5, 0);
  } else {
    int tb = bid - 32 * MAXTILES;       // 8192 blocks: w2 [E][4096][1024] -> w2t
    transpose_body<F_DIM, H_DIM>(w2, w2t, tb & 15, (tb >> 4) & 63, tb >> 10,
                                 (u16(*)[66])sh);
  }
}

// ---------------- GEMM2 (1-D, guard-aware XCD swizzle, split-K=4, bf16) ----
__global__ __launch_bounds__(256, 4) void gemm2_kernel(
    const u16* __restrict__ gb, const u16* __restrict__ w2t,
    const int4* __restrict__ tiles, const int* __restrict__ ntiles,
    u16* __restrict__ ypart){
  __shared__ __align__(16) u16 sh[2 * 128 * 64];
  int bid = blockIdx.x;                  // grid 8 * MAXTILES * KSPLIT
  int nt = *ntiles;
  int nwork = nt * 8 * KSPLIT;
  if (bid >= nwork) return;
  int w = xcd_chunk(bid, nwork);
  int col = w & 7;
  int tz  = w >> 3;                      // z*nt + tile: same-z neighbors share B
  int tile = tz % nt, z = tz / nt;
  gemm_body<H_DIM, F_DIM, 16, 2>(sh, sh + 8192, gb, w2t, tiles,
                                 ypart, nullptr, (size_t)M_SLOT * H_DIM,
                                 col, tile, z);
}

// ---------------- combine: sum KSPLIT bf16 partials, weighted ----------------
__global__ __launch_bounds__(256) void combine_kernel(const u16* __restrict__ yp,
                                                      const int* __restrict__ dest,
                                                      const float* __restrict__ tok_p,
                                                      float* __restrict__ out){
  int t = blockIdx.x;
  int d0 = dest[2*t], d1 = dest[2*t+1];
  float p0 = tok_p[2*t], p1 = tok_p[2*t+1];
  float4 r; r.x = 0.f; r.y = 0.f; r.z = 0.f; r.w = 0.f;
  #pragma unroll
  for (int s = 0; s < KSPLIT; s++){
    ushort4 a = ((const ushort4*)(yp + ((size_t)s * M_SLOT + d0) * H_DIM))[threadIdx.x];
    ushort4 b = ((const ushort4*)(yp + ((size_t)s * M_SLOT + d1) * H_DIM))[threadIdx.x];
    r.x += p0*bf2f(a.x) + p1*bf2f(b.x); r.y += p0*bf2f(a.y) + p1*bf2f(b.y);
    r.z += p0*bf2f(a.z) + p1*bf2f(b.z); r.w += p0*bf2f(a.w) + p1*bf2f(b.w);
  }
  ((float4*)(out + (size_t)t * H_DIM))[threadIdx.x] = r;
}

extern "C" void kernel_launch(void* const* d_in, const int* in_sizes, int n_in,
                              void* d_out, int out_size, void* d_ws, size_t ws_size,
                              hipStream_t stream) {
  const float* x  = (const float*)d_in[0];
  const float* rw = (const float*)d_in[1];
  const float* w1 = (const float*)d_in[2];
  const float* w2 = (const float*)d_in[3];
  float* out_mlp  = (float*)d_out;
  float* out_gelu = (float*)d_out + (size_t)T_TOK * H_DIM;

  char* ws = (char*)d_ws;
  // ypart [4][M][H] bf16 (32 MB) aliases w1t (dead after GEMM1)
  u16*   w1t   = (u16*)(ws + 0);                 // [E][F][H] bf16, 64 MB
  u16*   ypart = (u16*)(ws + 0);                 // alias
  u16*   w2t   = (u16*)(ws + 67108864);          // [E][H][F] bf16, 64 MB
  u16*   xg    = (u16*)(ws + 134217728);         // [M+128][H] bf16
  u16*   gb    = (u16*)(ws + 143130624);         // [M+128][F] bf16
  char*  small = ws + 178782208;
  int*   tok_e = (int*)(small);
  float* tok_p = (float*)(small + 16384);
  int*   dest  = (int*)(small + 32768);
  int4*  tiles = (int4*)(small + 53248);
  int*   ntiles = (int*)(small + 54272);

  router_tw1_kernel<<<T_TOK/4 + 8192, 256, 0, stream>>>(x, rw, tok_e, tok_p, w1, w1t);
  route_pack_kernel<<<1, 256, 0, stream>>>(tok_e, dest, tiles, ntiles);
  gather_kernel<<<M_SLOT, 256, 0, stream>>>(x, dest, xg);
  gemm1_tw2_kernel<<<32 * MAXTILES + 8192, 256, 0, stream>>>(
      xg, w1t, tiles, ntiles, out_gelu, gb, w2, w2t);
  gemm2_kernel<<<8 * MAXTILES * KSPLIT, 256, 0, stream>>>(
      gb, w2t, tiles, ntiles, ypart);
  combine_kernel<<<T_TOK, 256, 0, stream>>>(ypart, dest, tok_p, out_mlp);
}